// Round 3
// baseline (6112.856 us; speedup 1.0000x reference)
//
#include <hip/hip_runtime.h>
#include <hip/hip_fp16.h>

#define N_USERS 100000
#define M_ITEMS 50000
#define N_NODES 150000
#define N_EDGES 6000000
#define DIM 64

#define VAL_BITS 14
#define VAL_MASK ((1u << VAL_BITS) - 1u)                  // 16383
#define VAL_SCALE 16383.0f
#define VAL_INV   (1.0f / 16383.0f)

#define NPB     196                                       // nodes per dst-bucket
#define N_BKT2  766                                       // ceil(150000/196) -> 3 blocks/CU, single cohort
#define NBIN    19                                        // src>>13 bins (8192 rows = 1 MB table span)
#define ACC_STRIDE 65                                     // bank-swizzle: 65 mod 32 = 1

#define P_BLK   256                                       // partition blocks
#define PT      512                                       // threads for count/scatter
#define CHUNK   ((N_EDGES + P_BLK - 1) / P_BLK)           // 23438 edges per block

// ---- init: h_cur(fp16) = concat(user_emb, item_emb) ----------------------------
__global__ void init_kernel(const float4* __restrict__ user_emb,
                            const float4* __restrict__ item_emb,
                            ushort4* __restrict__ h_cur) {
    const int n_user4 = N_USERS * DIM / 4;
    const int n_tot4  = N_NODES * DIM / 4;
    int i = blockIdx.x * blockDim.x + threadIdx.x;
    if (i < n_tot4) {
        float4 v = (i < n_user4) ? user_emb[i] : item_emb[i - n_user4];
        ushort4 hv;
        hv.x = __half_as_ushort(__float2half_rn(v.x));
        hv.y = __half_as_ushort(__float2half_rn(v.y));
        hv.z = __half_as_ushort(__float2half_rn(v.z));
        hv.w = __half_as_ushort(__float2half_rn(v.w));
        h_cur[i] = hv;
    }
}

// ---- pass 1: per-(block,bucket) histogram via LDS ------------------------------
__global__ __launch_bounds__(PT) void count_kernel(const int* __restrict__ dst,
                                                   int* __restrict__ cnt) {  // [P_BLK][N_BKT2]
    __shared__ int hist[N_BKT2];
    int p = blockIdx.x, tid = threadIdx.x;
    for (int i = tid; i < N_BKT2; i += PT) hist[i] = 0;
    __syncthreads();
    int beg = p * CHUNK;
    int end = min(beg + CHUNK, N_EDGES);
    for (int e = beg + tid; e < end; e += PT) {
        unsigned int d = (unsigned int)__builtin_nontemporal_load(&dst[e]);
        atomicAdd(&hist[d / NPB], 1);
    }
    __syncthreads();
    for (int i = tid; i < N_BKT2; i += PT) cnt[p * N_BKT2 + i] = hist[i];
}

// ---- per-bucket exclusive scan over blocks (in place); emit bucket totals ------
__global__ __launch_bounds__(P_BLK) void colscan_kernel(int* __restrict__ cnt,     // [P_BLK][N_BKT2]
                                                        int* __restrict__ totals) {// [N_BKT2]
    __shared__ int lds[P_BLK];
    int b = blockIdx.x, tid = threadIdx.x;
    int v = cnt[tid * N_BKT2 + b];
    lds[tid] = v;
    __syncthreads();
    for (int off = 1; off < P_BLK; off <<= 1) {
        int t = (tid >= off) ? lds[tid - off] : 0;
        __syncthreads();
        lds[tid] += t;
        __syncthreads();
    }
    cnt[tid * N_BKT2 + b] = lds[tid] - v;                 // exclusive within bucket
    if (tid == P_BLK - 1) totals[b] = lds[P_BLK - 1];
}

// ---- exclusive scan of 766 bucket totals -> bucket_base; one block -------------
__global__ __launch_bounds__(1024) void bucket_scan_kernel(const int* __restrict__ totals,
                                                           int* __restrict__ bucket_base) {
    __shared__ int lds[1024];
    int tid = threadIdx.x;
    int v = (tid < N_BKT2) ? totals[tid] : 0;
    lds[tid] = v;
    __syncthreads();
    for (int off = 1; off < 1024; off <<= 1) {
        int t = (tid >= off) ? lds[tid - off] : 0;
        __syncthreads();
        lds[tid] += t;
        __syncthreads();
    }
    if (tid < N_BKT2) bucket_base[tid] = lds[tid] - v;    // exclusive
    if (tid == 0) bucket_base[N_BKT2] = N_EDGES;
}

// ---- pass 2: deterministic scatter into private contiguous (block,bucket) runs -
// payload = (src << 14) | round(val * 16383)
__global__ __launch_bounds__(PT) void scatter_kernel(const int* __restrict__ src,
                                                     const int* __restrict__ dst,
                                                     const float* __restrict__ val,
                                                     const int* __restrict__ bucket_base,
                                                     const int* __restrict__ cnt,
                                                     uint2* __restrict__ bucketed) {
    __shared__ int lofs[N_BKT2];
    int p = blockIdx.x, tid = threadIdx.x;
    for (int i = tid; i < N_BKT2; i += PT)
        lofs[i] = bucket_base[i] + cnt[p * N_BKT2 + i];
    __syncthreads();
    int beg = p * CHUNK;
    int end = min(beg + CHUNK, N_EDGES);
    for (int e = beg + tid; e < end; e += PT) {
        unsigned int d = (unsigned int)__builtin_nontemporal_load(&dst[e]);
        int s = __builtin_nontemporal_load(&src[e]);
        float w = __builtin_nontemporal_load(&val[e]);
        unsigned int q = __float2uint_rn(w * VAL_SCALE);
        unsigned int payload = ((unsigned int)s << VAL_BITS) | q;
        int pos = atomicAdd(&lofs[d / NPB], 1);           // LDS atomic only
        bucketed[pos] = make_uint2(d, payload);
    }
}

// ---- per-bucket 19-bin counting sort by src_hi -> (pay, loc) split arrays ------
__global__ __launch_bounds__(256) void sort_kernel(const uint2* __restrict__ bucketed,
                                                   const int* __restrict__ bucket_base,
                                                   unsigned int* __restrict__ csr_pay,
                                                   unsigned char* __restrict__ csr_loc) {
    __shared__ int histo[NBIN];
    __shared__ int cur[NBIN];
    int tid = threadIdx.x, b = blockIdx.x;
    int node0 = b * NPB;
    int rbeg = bucket_base[b];
    int rend = bucket_base[b + 1];
    if (tid < NBIN) histo[tid] = 0;
    __syncthreads();
    for (int i = rbeg + tid; i < rend; i += 256) {
        uint2 e = bucketed[i];
        atomicAdd(&histo[e.y >> 27], 1);                  // src>>13 = payload>>27
    }
    __syncthreads();
    if (tid == 0) {
        int run = 0;
        for (int i = 0; i < NBIN; ++i) { cur[i] = run; run += histo[i]; }
    }
    __syncthreads();
    for (int i = rbeg + tid; i < rend; i += 256) {
        uint2 e = bucketed[i];
        int pos = rbeg + atomicAdd(&cur[e.y >> 27], 1);
        csr_pay[pos] = e.y;
        csr_loc[pos] = (unsigned char)(e.x - (unsigned int)node0);
    }
}

// ---- sweep SpMM: one block per 196-node bucket; src-ordered edges;
//      fp32 LDS accumulation via ds_add_f32 (stride-65 bank swizzle) -------------
#define EDGE_ACC(P, L, R) { \
    float ww = (float)((P) & VAL_MASK) * VAL_INV; \
    float2 f0 = __half22float2(*(const __half2*)&R.x); \
    float2 f1 = __half22float2(*(const __half2*)&R.y); \
    float2 f2 = __half22float2(*(const __half2*)&R.z); \
    float2 f3 = __half22float2(*(const __half2*)&R.w); \
    float* ab = &accs[(L) * ACC_STRIDE + sub * 8]; \
    atomicAdd(ab + 0, ww * f0.x); atomicAdd(ab + 1, ww * f0.y); \
    atomicAdd(ab + 2, ww * f1.x); atomicAdd(ab + 3, ww * f1.y); \
    atomicAdd(ab + 4, ww * f2.x); atomicAdd(ab + 5, ww * f2.y); \
    atomicAdd(ab + 6, ww * f3.x); atomicAdd(ab + 7, ww * f3.y); }

__global__ __launch_bounds__(256, 3) void spmm_sweep(const int* __restrict__ bucket_base,
                                                     const unsigned int* __restrict__ csr_pay,
                                                     const unsigned char* __restrict__ csr_loc,
                                                     const __half* __restrict__ h_in,
                                                     __half* __restrict__ h_out,
                                                     const __half* __restrict__ h1,
                                                     const float* __restrict__ user_emb,
                                                     const float* __restrict__ item_emb,
                                                     float* __restrict__ out,
                                                     int last) {
    __shared__ float accs[NPB * ACC_STRIDE];              // 50,960 B
    int tid = threadIdx.x;
    int w   = tid >> 6;
    int lane = tid & 63;
    int eg  = lane >> 3;                                  // edge within octet
    int sub = lane & 7;                                   // 8-elem dim group
    int b = blockIdx.x;
    int node0 = b * NPB;

    for (int i = tid; i < NPB * ACC_STRIDE; i += 256) accs[i] = 0.f;
    __syncthreads();

    int rbeg = bucket_base[b];
    int rend = bucket_base[b + 1];

    // 4 waves interleaved at 16-edge granularity: synchronized src sweep
    for (int e0 = rbeg + w * 16; e0 < rend; e0 += 64) {
        int ea = e0 + eg;
        int eb = e0 + 8 + eg;
        bool va = ea < rend, vb = eb < rend;
        unsigned int pa = __builtin_nontemporal_load(&csr_pay[ea]);   // padded alloc
        unsigned int pb = __builtin_nontemporal_load(&csr_pay[eb]);
        int la = csr_loc[ea];
        int lb = csr_loc[eb];
        if (!va) { pa = 0u; la = 0; }
        if (!vb) { pb = 0u; lb = 0; }
        uint4 ra = *((const uint4*)(h_in + (size_t)(pa >> VAL_BITS) * DIM) + sub);
        uint4 rb = *((const uint4*)(h_in + (size_t)(pb >> VAL_BITS) * DIM) + sub);
        EDGE_ACC(pa, la, ra)
        EDGE_ACC(pb, lb, rb)
    }
    __syncthreads();

    // epilogue: stream bucket rows out, coalesced
    int nb = min(NPB, N_NODES - node0);
    if (!last) {
        for (int q = tid; q < nb * 4; q += 256) {
            int n = q >> 2, qq = q & 3;
            const float* a = &accs[n * ACC_STRIDE + qq * 16];
            __half2 h0 = __floats2half2_rn(a[0],  a[1]);
            __half2 h1v= __floats2half2_rn(a[2],  a[3]);
            __half2 h2 = __floats2half2_rn(a[4],  a[5]);
            __half2 h3 = __floats2half2_rn(a[6],  a[7]);
            __half2 h4 = __floats2half2_rn(a[8],  a[9]);
            __half2 h5 = __floats2half2_rn(a[10], a[11]);
            __half2 h6 = __floats2half2_rn(a[12], a[13]);
            __half2 h7 = __floats2half2_rn(a[14], a[15]);
            uint4 w0, w1;
            w0.x = *(const unsigned int*)&h0; w0.y = *(const unsigned int*)&h1v;
            w0.z = *(const unsigned int*)&h2; w0.w = *(const unsigned int*)&h3;
            w1.x = *(const unsigned int*)&h4; w1.y = *(const unsigned int*)&h5;
            w1.z = *(const unsigned int*)&h6; w1.w = *(const unsigned int*)&h7;
            size_t o = (size_t)(node0 + n) * DIM + (size_t)qq * 16;
            uint4* hp = (uint4*)(h_out + o);
            hp[0] = w0;
            hp[1] = w1;
        }
    } else {
        for (int q = tid; q < nb * 4; q += 256) {
            int n = q >> 2, qq = q & 3;
            int node = node0 + n;
            size_t o = (size_t)node * DIM + (size_t)qq * 16;
            const float* a = &accs[n * ACC_STRIDE + qq * 16];
            uint4 a1 = *(const uint4*)(h1 + o);
            uint4 a1b = *(const uint4*)(h1 + o + 8);
            uint4 a2 = *(const uint4*)(h_in + o);
            uint4 a2b = *(const uint4*)(h_in + o + 8);
            const float* ebase = (node < N_USERS) ? (user_emb + o)
                                                  : (item_emb + (o - (size_t)N_USERS * DIM));
            float hv[16], gv[16];
            ((uint4*)0, 0);
            {
                const __half2* p1 = (const __half2*)&a1;
                const __half2* p1b = (const __half2*)&a1b;
                const __half2* p2 = (const __half2*)&a2;
                const __half2* p2b = (const __half2*)&a2b;
                #pragma unroll
                for (int k = 0; k < 4; ++k) {
                    float2 x = __half22float2(p1[k]);  hv[2*k]   = x.x; hv[2*k+1]   = x.y;
                    float2 y = __half22float2(p1b[k]); hv[8+2*k] = y.x; hv[8+2*k+1] = y.y;
                    float2 u = __half22float2(p2[k]);  gv[2*k]   = u.x; gv[2*k+1]   = u.y;
                    float2 v = __half22float2(p2b[k]); gv[8+2*k] = v.x; gv[8+2*k+1] = v.y;
                }
            }
            float4 r[4];
            #pragma unroll
            for (int k = 0; k < 4; ++k) {
                float4 e = ((const float4*)ebase)[k];
                r[k].x = (e.x + hv[4*k]   + gv[4*k]   + a[4*k])   * 0.25f;
                r[k].y = (e.y + hv[4*k+1] + gv[4*k+1] + a[4*k+1]) * 0.25f;
                r[k].z = (e.z + hv[4*k+2] + gv[4*k+2] + a[4*k+2]) * 0.25f;
                r[k].w = (e.w + hv[4*k+3] + gv[4*k+3] + a[4*k+3]) * 0.25f;
            }
            float4* op = (float4*)(out + o);
            #pragma unroll
            for (int k = 0; k < 4; ++k) op[k] = r[k];
        }
    }
}

extern "C" void kernel_launch(void* const* d_in, const int* in_sizes, int n_in,
                              void* d_out, int out_size, void* d_ws, size_t ws_size,
                              hipStream_t stream) {
    const float* user_emb = (const float*)d_in[0];
    const float* item_emb = (const float*)d_in[1];
    const int*   edge_src = (const int*)d_in[2];
    const int*   edge_dst = (const int*)d_in[3];
    const float* edge_val = (const float*)d_in[4];
    float* out = (float*)d_out;

    // ---- workspace layout ----
    char* p = (char*)d_ws;
    __half* h_a = (__half*)p;                  p += (size_t)N_NODES * DIM * 2;        // 19.2 MB
    unsigned int* csr_pay = (unsigned int*)p;  p += (size_t)(N_EDGES + 256) * 4;      // 24 MB (+pad)
    unsigned char* csr_loc = (unsigned char*)p;p += (size_t)(N_EDGES + 1024);         // 6 MB (+pad)
    int* bucket_base = (int*)p;                p += (size_t)(N_BKT2 + 16) * 4;
    int* totals = (int*)p;                     p += (size_t)(N_BKT2 + 16) * 4;
    int* cnt = (int*)p;                        p += (size_t)P_BLK * N_BKT2 * 4;       // 784 KB
    // union region: bucketed (build phase, 48 MB) / h_b (pull phase, 19.2 MB)
    uint2*  bucketed = (uint2*)p;
    __half* h_b      = (__half*)p;

    const int n4 = N_NODES * DIM / 4;
    const int ew_blocks = (n4 + 255) / 256;

    // ---- build bucketed+src-sorted edge lists (no global atomics) ----
    init_kernel<<<ew_blocks, 256, 0, stream>>>((const float4*)user_emb,
                                               (const float4*)item_emb,
                                               (ushort4*)h_a);
    count_kernel<<<P_BLK, PT, 0, stream>>>(edge_dst, cnt);
    colscan_kernel<<<N_BKT2, P_BLK, 0, stream>>>(cnt, totals);
    bucket_scan_kernel<<<1, 1024, 0, stream>>>(totals, bucket_base);
    scatter_kernel<<<P_BLK, PT, 0, stream>>>(edge_src, edge_dst, edge_val,
                                             bucket_base, cnt, bucketed);
    sort_kernel<<<N_BKT2, 256, 0, stream>>>(bucketed, bucket_base, csr_pay, csr_loc);

    // ---- 3 sweep layers; acc deferred into layer-3 epilogue ----
    // L1: h_a(h0) -> h_b(h1);  L2: h_b(h1) -> h_a(h2);  L3: h_a(h2) -> out
    spmm_sweep<<<N_BKT2, 256, 0, stream>>>(bucket_base, csr_pay, csr_loc, h_a, h_b,
                                           h_b, user_emb, item_emb, out, 0);
    spmm_sweep<<<N_BKT2, 256, 0, stream>>>(bucket_base, csr_pay, csr_loc, h_b, h_a,
                                           h_b, user_emb, item_emb, out, 0);
    spmm_sweep<<<N_BKT2, 256, 0, stream>>>(bucket_base, csr_pay, csr_loc, h_a, h_b,
                                           h_b, user_emb, item_emb, out, 1);
}